// Round 1
// baseline (248.283 us; speedup 1.0000x reference)
//
#include <hip/hip_runtime.h>
#include <hip/hip_bf16.h>
#include <stdint.h>

#define NB 2
#define LQ 2048
#define DMODEL 1024
#define NH 8
#define DH 128
#define KWIN 64

typedef __attribute__((ext_vector_type(8))) short short8;
typedef __attribute__((ext_vector_type(4))) float f32x4;

__device__ __forceinline__ ushort f2bf(float f) {
  uint u = __float_as_uint(f);
  return (ushort)((u + 0x7fffu + ((u >> 16) & 1u)) >> 16);
}
__device__ __forceinline__ float bflo(uint u) { return __uint_as_float(u << 16); }
__device__ __forceinline__ float bfhi(uint u) { return __uint_as_float(u & 0xffff0000u); }

// ---------------- conversion kernels (f32 -> bf16) ----------------
__global__ void cvt_qkv(const float4* __restrict__ a, const float4* __restrict__ b,
                        const float4* __restrict__ c, ushort* __restrict__ da,
                        ushort* __restrict__ db, ushort* __restrict__ dc, int n4) {
  int stride = gridDim.x * blockDim.x;
  for (int i = blockIdx.x * blockDim.x + threadIdx.x; i < n4; i += stride) {
    float4 x = a[i], y = b[i], z = c[i];
    ushort4 xo = make_ushort4(f2bf(x.x), f2bf(x.y), f2bf(x.z), f2bf(x.w));
    ushort4 yo = make_ushort4(f2bf(y.x), f2bf(y.y), f2bf(y.z), f2bf(y.w));
    ushort4 zo = make_ushort4(f2bf(z.x), f2bf(z.y), f2bf(z.z), f2bf(z.w));
    *(ushort4*)(da + 4 * (size_t)i) = xo;
    *(ushort4*)(db + 4 * (size_t)i) = yo;
    *(ushort4*)(dc + 4 * (size_t)i) = zo;
  }
}

__global__ void cvt_w(const float4* __restrict__ a, const float4* __restrict__ b,
                      const float4* __restrict__ c, const float4* __restrict__ d,
                      ushort* __restrict__ da, ushort* __restrict__ db,
                      ushort* __restrict__ dc, ushort* __restrict__ dd, int n4) {
  int stride = gridDim.x * blockDim.x;
  for (int i = blockIdx.x * blockDim.x + threadIdx.x; i < n4; i += stride) {
    float4 x = a[i], y = b[i], z = c[i], w = d[i];
    *(ushort4*)(da + 4 * (size_t)i) = make_ushort4(f2bf(x.x), f2bf(x.y), f2bf(x.z), f2bf(x.w));
    *(ushort4*)(db + 4 * (size_t)i) = make_ushort4(f2bf(y.x), f2bf(y.y), f2bf(y.z), f2bf(y.w));
    *(ushort4*)(dc + 4 * (size_t)i) = make_ushort4(f2bf(z.x), f2bf(z.y), f2bf(z.z), f2bf(z.w));
    *(ushort4*)(dd + 4 * (size_t)i) = make_ushort4(f2bf(w.x), f2bf(w.y), f2bf(w.z), f2bf(w.w));
  }
}

// ---------------- bf16 MFMA GEMM: C[M,N] = A[M,K] * Bt[N,K]^T + bias[N] ----------------
// 128x128 tile, BK=32, 256 threads (2x2 waves of 64x64), global_load_lds staging.
// blockIdx.z selects one of three (A,Bt,bias,C) pointer sets (fused QKV).
template <int OUT_BF16>
__global__ __launch_bounds__(256, 2) void gemm_bt(
    const ushort* __restrict__ A0, const ushort* __restrict__ B0,
    const float* __restrict__ c0, void* __restrict__ D0,
    const ushort* __restrict__ A1, const ushort* __restrict__ B1,
    const float* __restrict__ c1, void* __restrict__ D1,
    const ushort* __restrict__ A2, const ushort* __restrict__ B2,
    const float* __restrict__ c2, void* __restrict__ D2,
    int M, int N, int Kd) {
  const int z = blockIdx.z;
  const ushort* A = (z == 0) ? A0 : ((z == 1) ? A1 : A2);
  const ushort* Bt = (z == 0) ? B0 : ((z == 1) ? B1 : B2);
  const float* bias = (z == 0) ? c0 : ((z == 1) ? c1 : c2);
  void* Cv = (z == 0) ? D0 : ((z == 1) ? D1 : D2);

  __shared__ ushort As[128 * 32];
  __shared__ ushort Bs[128 * 32];

  const int tid = threadIdx.x;
  const int wave = tid >> 6, lane = tid & 63;
  const int wm = wave >> 1, wn = wave & 1;
  const int lrow = lane & 15, kgrp = lane >> 4;

  const int m0 = blockIdx.y * 128, n0 = blockIdx.x * 128;

  // staging: two 4KB rounds per 8KB tile; thread t stages 16B at byte t*16 (+4096)
  const int b0 = tid * 16;
  const int b1 = b0 + 4096;
  const int r0 = b0 >> 6, cc0 = (b0 & 63) >> 1;  // row, col-elem within tile
  const int r1 = b1 >> 6, cc1 = (b1 & 63) >> 1;

  f32x4 acc[4][4] = {};

  for (int kt = 0; kt < Kd; kt += 32) {
    __builtin_amdgcn_global_load_lds(
        (const __attribute__((address_space(1))) void*)(A + (size_t)(m0 + r0) * Kd + kt + cc0),
        (__attribute__((address_space(3))) void*)(As + (b0 >> 1)), 16, 0, 0);
    __builtin_amdgcn_global_load_lds(
        (const __attribute__((address_space(1))) void*)(A + (size_t)(m0 + r1) * Kd + kt + cc1),
        (__attribute__((address_space(3))) void*)(As + (b1 >> 1)), 16, 0, 0);
    __builtin_amdgcn_global_load_lds(
        (const __attribute__((address_space(1))) void*)(Bt + (size_t)(n0 + r0) * Kd + kt + cc0),
        (__attribute__((address_space(3))) void*)(Bs + (b0 >> 1)), 16, 0, 0);
    __builtin_amdgcn_global_load_lds(
        (const __attribute__((address_space(1))) void*)(Bt + (size_t)(n0 + r1) * Kd + kt + cc1),
        (__attribute__((address_space(3))) void*)(Bs + (b1 >> 1)), 16, 0, 0);
    __syncthreads();  // drains vmcnt -> staged data visible

    short8 af[4], bfr[4];
#pragma unroll
    for (int m = 0; m < 4; ++m)
      af[m] = *(const short8*)(As + (wm * 64 + m * 16 + lrow) * 32 + kgrp * 8);
#pragma unroll
    for (int n = 0; n < 4; ++n)
      bfr[n] = *(const short8*)(Bs + (wn * 64 + n * 16 + lrow) * 32 + kgrp * 8);
#pragma unroll
    for (int m = 0; m < 4; ++m)
#pragma unroll
      for (int n = 0; n < 4; ++n)
        acc[m][n] = __builtin_amdgcn_mfma_f32_16x16x32_bf16(af[m], bfr[n], acc[m][n], 0, 0, 0);
    __syncthreads();
  }

  // epilogue: C/D layout col=lane&15, row=(lane>>4)*4+j  (verified m89/m91)
  const int cbase = n0 + wn * 64;
  const int rbase = m0 + wm * 64;
  float bv[4];
#pragma unroll
  for (int n = 0; n < 4; ++n) bv[n] = bias[cbase + n * 16 + lrow];

#pragma unroll
  for (int m = 0; m < 4; ++m) {
#pragma unroll
    for (int n = 0; n < 4; ++n) {
      const int col = cbase + n * 16 + lrow;
#pragma unroll
      for (int j = 0; j < 4; ++j) {
        const int row = rbase + m * 16 + kgrp * 4 + j;
        float val = acc[m][n][j] + bv[n];
        if (OUT_BF16) {
          ((ushort*)Cv)[(size_t)row * N + col] = f2bf(val);
        } else {
          ((float*)Cv)[(size_t)row * N + col] = val;
        }
      }
    }
  }
}

// ---------------- banded attention (one wave per (b,h,l), online softmax) ----------------
__global__ __launch_bounds__(256) void banded_attn(const ushort* __restrict__ qp,
                                                   const ushort* __restrict__ kp,
                                                   const ushort* __restrict__ vp,
                                                   ushort* __restrict__ ao) {
  const int lane = threadIdx.x & 63;
  const int gid = blockIdx.x * 4 + (threadIdx.x >> 6);  // (b,h,l) flat, l fastest
  const int l = gid & (LQ - 1);
  const int h = (gid >> 11) & (NH - 1);
  const int b = gid >> 14;
  const int dil = 1 << (h >> 1);  // 1,1,2,2,4,4,8,8

  const size_t rowstride = (size_t)NH * DH;
  const ushort* qrow = qp + ((size_t)(b * LQ + l) * NH + h) * DH;
  const uint qu = *(const uint*)(qrow + 2 * lane);
  const float q0 = bflo(qu), q1 = bfhi(qu);

  const ushort* kbase = kp + ((size_t)b * LQ * NH + h) * (size_t)DH;
  const ushort* vbase = vp + ((size_t)b * LQ * NH + h) * (size_t)DH;

  float mx = -1e30f, den = 0.f, a0 = 0.f, a1 = 0.f;
  for (int j = 0; j < KWIN; ++j) {
    const int p = l + (j - 31) * dil;
    if ((unsigned)p < (unsigned)LQ) {
      const uint ku = *(const uint*)(kbase + (size_t)p * rowstride + 2 * lane);
      float part = q0 * bflo(ku) + q1 * bfhi(ku);
#pragma unroll
      for (int off = 32; off > 0; off >>= 1) part += __shfl_xor(part, off);
      const uint vu = *(const uint*)(vbase + (size_t)p * rowstride + 2 * lane);
      const float s = part;
      const float mn = fmaxf(mx, s);
      const float sc = __expf(mx - mn);
      const float w = __expf(s - mn);
      a0 = a0 * sc + w * bflo(vu);
      a1 = a1 * sc + w * bfhi(vu);
      den = den * sc + w;
      mx = mn;
    }
  }
  const float inv = 1.f / den;
  ushort* orow = ao + ((size_t)(b * LQ + l) * NH + h) * DH;
  *(uint*)(orow + 2 * lane) = (uint)f2bf(a0 * inv) | ((uint)f2bf(a1 * inv) << 16);
}

// ---------------- launch ----------------
extern "C" void kernel_launch(void* const* d_in, const int* in_sizes, int n_in,
                              void* d_out, int out_size, void* d_ws, size_t ws_size,
                              hipStream_t stream) {
  const float* q = (const float*)d_in[0];
  const float* k = (const float*)d_in[1];
  const float* v = (const float*)d_in[2];
  const float* Wq = (const float*)d_in[3];
  const float* bq = (const float*)d_in[4];
  const float* Wk = (const float*)d_in[5];
  const float* bk = (const float*)d_in[6];
  const float* Wv = (const float*)d_in[7];
  const float* bv = (const float*)d_in[8];
  const float* Wc = (const float*)d_in[9];
  const float* bc = (const float*)d_in[10];

  const size_t NIN = (size_t)NB * LQ * DMODEL;   // 4,194,304
  const size_t NW = (size_t)NH * DH * DMODEL;    // 1,048,576

  ushort* qin = (ushort*)d_ws;
  ushort* kin = qin + NIN;
  ushort* vin = kin + NIN;
  ushort* wqb = vin + NIN;
  ushort* wkb = wqb + NW;
  ushort* wvb = wkb + NW;
  ushort* wcb = wvb + NW;
  ushort* qp = wcb + NW;
  ushort* kp = qp + NIN;
  ushort* vp = kp + NIN;
  ushort* aob = vp + NIN;  // total 7*NIN + 4*NW ushorts = ~67 MB

  hipLaunchKernelGGL(cvt_qkv, dim3(2048), dim3(256), 0, stream,
                     (const float4*)q, (const float4*)k, (const float4*)v,
                     qin, kin, vin, (int)(NIN / 4));
  hipLaunchKernelGGL(cvt_w, dim3(1024), dim3(256), 0, stream,
                     (const float4*)Wq, (const float4*)Wk, (const float4*)Wv, (const float4*)Wc,
                     wqb, wkb, wvb, wcb, (int)(NW / 4));

  // fused QKV projections: grid.z picks (input, weight, bias, out)
  dim3 g1(DMODEL / 128, (NB * LQ) / 128, 3);
  hipLaunchKernelGGL((gemm_bt<1>), g1, dim3(256), 0, stream,
                     qin, wqb, bq, (void*)qp,
                     kin, wkb, bk, (void*)kp,
                     vin, wvb, bv, (void*)vp,
                     NB * LQ, DMODEL, DMODEL);

  hipLaunchKernelGGL(banded_attn, dim3(NB * NH * LQ / 4), dim3(256), 0, stream,
                     qp, kp, vp, aob);

  dim3 g2(DMODEL / 128, (NB * LQ) / 128, 1);
  hipLaunchKernelGGL((gemm_bt<0>), g2, dim3(256), 0, stream,
                     aob, wcb, bc, d_out,
                     aob, wcb, bc, d_out,
                     aob, wcb, bc, d_out,
                     NB * LQ, DMODEL, DMODEL);
}

// Round 2
// 106.939 us; speedup vs baseline: 2.3217x; 2.3217x over previous
//
#include <hip/hip_runtime.h>
#include <hip/hip_bf16.h>
#include <stdint.h>

#define NB 2
#define LQ 2048
#define DMODEL 1024
#define NH 8
#define DH 128
#define KWIN 64

typedef __attribute__((ext_vector_type(8))) short short8;
typedef __attribute__((ext_vector_type(4))) float f32x4;

__device__ __forceinline__ ushort f2bf(float f) {
  uint u = __float_as_uint(f);
  return (ushort)((u + 0x7fffu + ((u >> 16) & 1u)) >> 16);
}
__device__ __forceinline__ float bflo(uint u) { return __uint_as_float(u << 16); }
__device__ __forceinline__ float bfhi(uint u) { return __uint_as_float(u & 0xffff0000u); }

// ---------------- conversion kernels (f32 -> bf16) ----------------
__global__ void cvt_qkv(const float4* __restrict__ a, const float4* __restrict__ b,
                        const float4* __restrict__ c, ushort* __restrict__ da,
                        ushort* __restrict__ db, ushort* __restrict__ dc, int n4) {
  int stride = gridDim.x * blockDim.x;
  for (int i = blockIdx.x * blockDim.x + threadIdx.x; i < n4; i += stride) {
    float4 x = a[i], y = b[i], z = c[i];
    *(ushort4*)(da + 4 * (size_t)i) = make_ushort4(f2bf(x.x), f2bf(x.y), f2bf(x.z), f2bf(x.w));
    *(ushort4*)(db + 4 * (size_t)i) = make_ushort4(f2bf(y.x), f2bf(y.y), f2bf(y.z), f2bf(y.w));
    *(ushort4*)(dc + 4 * (size_t)i) = make_ushort4(f2bf(z.x), f2bf(z.y), f2bf(z.z), f2bf(z.w));
  }
}

__global__ void cvt_w(const float4* __restrict__ a, const float4* __restrict__ b,
                      const float4* __restrict__ c, const float4* __restrict__ d,
                      ushort* __restrict__ da, ushort* __restrict__ db,
                      ushort* __restrict__ dc, ushort* __restrict__ dd, int n4) {
  int stride = gridDim.x * blockDim.x;
  for (int i = blockIdx.x * blockDim.x + threadIdx.x; i < n4; i += stride) {
    float4 x = a[i], y = b[i], z = c[i], w = d[i];
    *(ushort4*)(da + 4 * (size_t)i) = make_ushort4(f2bf(x.x), f2bf(x.y), f2bf(x.z), f2bf(x.w));
    *(ushort4*)(db + 4 * (size_t)i) = make_ushort4(f2bf(y.x), f2bf(y.y), f2bf(y.z), f2bf(y.w));
    *(ushort4*)(dc + 4 * (size_t)i) = make_ushort4(f2bf(z.x), f2bf(z.y), f2bf(z.z), f2bf(z.w));
    *(ushort4*)(dd + 4 * (size_t)i) = make_ushort4(f2bf(w.x), f2bf(w.y), f2bf(w.z), f2bf(w.w));
  }
}

// ---------------- bf16 MFMA GEMM: C[M,N] = A[M,K] * Bt[N,K]^T + bias[N] ----------------
template <int OUT_BF16>
__global__ __launch_bounds__(256, 2) void gemm_bt(
    const ushort* __restrict__ A0, const ushort* __restrict__ B0,
    const float* __restrict__ c0, void* __restrict__ D0,
    const ushort* __restrict__ A1, const ushort* __restrict__ B1,
    const float* __restrict__ c1, void* __restrict__ D1,
    const ushort* __restrict__ A2, const ushort* __restrict__ B2,
    const float* __restrict__ c2, void* __restrict__ D2,
    int M, int N, int Kd) {
  const int z = blockIdx.z;
  const ushort* A = (z == 0) ? A0 : ((z == 1) ? A1 : A2);
  const ushort* Bt = (z == 0) ? B0 : ((z == 1) ? B1 : B2);
  const float* bias = (z == 0) ? c0 : ((z == 1) ? c1 : c2);
  void* Cv = (z == 0) ? D0 : ((z == 1) ? D1 : D2);

  __shared__ ushort As[128 * 32];
  __shared__ ushort Bs[128 * 32];

  const int tid = threadIdx.x;
  const int wave = tid >> 6, lane = tid & 63;
  const int wm = wave >> 1, wn = wave & 1;
  const int lrow = lane & 15, kgrp = lane >> 4;

  const int m0 = blockIdx.y * 128, n0 = blockIdx.x * 128;

  const int b0 = tid * 16;
  const int b1 = b0 + 4096;
  const int r0 = b0 >> 6, cc0 = (b0 & 63) >> 1;
  const int r1 = b1 >> 6, cc1 = (b1 & 63) >> 1;

  f32x4 acc[4][4] = {};

  for (int kt = 0; kt < Kd; kt += 32) {
    __builtin_amdgcn_global_load_lds(
        (const __attribute__((address_space(1))) void*)(A + (size_t)(m0 + r0) * Kd + kt + cc0),
        (__attribute__((address_space(3))) void*)(As + (b0 >> 1)), 16, 0, 0);
    __builtin_amdgcn_global_load_lds(
        (const __attribute__((address_space(1))) void*)(A + (size_t)(m0 + r1) * Kd + kt + cc1),
        (__attribute__((address_space(3))) void*)(As + (b1 >> 1)), 16, 0, 0);
    __builtin_amdgcn_global_load_lds(
        (const __attribute__((address_space(1))) void*)(Bt + (size_t)(n0 + r0) * Kd + kt + cc0),
        (__attribute__((address_space(3))) void*)(Bs + (b0 >> 1)), 16, 0, 0);
    __builtin_amdgcn_global_load_lds(
        (const __attribute__((address_space(1))) void*)(Bt + (size_t)(n0 + r1) * Kd + kt + cc1),
        (__attribute__((address_space(3))) void*)(Bs + (b1 >> 1)), 16, 0, 0);
    __syncthreads();

    short8 af[4], bfr[4];
#pragma unroll
    for (int m = 0; m < 4; ++m)
      af[m] = *(const short8*)(As + (wm * 64 + m * 16 + lrow) * 32 + kgrp * 8);
#pragma unroll
    for (int n = 0; n < 4; ++n)
      bfr[n] = *(const short8*)(Bs + (wn * 64 + n * 16 + lrow) * 32 + kgrp * 8);
#pragma unroll
    for (int m = 0; m < 4; ++m)
#pragma unroll
      for (int n = 0; n < 4; ++n)
        acc[m][n] = __builtin_amdgcn_mfma_f32_16x16x32_bf16(af[m], bfr[n], acc[m][n], 0, 0, 0);
    __syncthreads();
  }

  const int cbase = n0 + wn * 64;
  const int rbase = m0 + wm * 64;
  float bv[4];
#pragma unroll
  for (int n = 0; n < 4; ++n) bv[n] = bias[cbase + n * 16 + lrow];

#pragma unroll
  for (int m = 0; m < 4; ++m) {
#pragma unroll
    for (int n = 0; n < 4; ++n) {
      const int col = cbase + n * 16 + lrow;
#pragma unroll
      for (int j = 0; j < 4; ++j) {
        const int row = rbase + m * 16 + kgrp * 4 + j;
        float val = acc[m][n][j] + bv[n];
        if (OUT_BF16) {
          ((ushort*)Cv)[(size_t)row * N + col] = f2bf(val);
        } else {
          ((float*)Cv)[(size_t)row * N + col] = val;
        }
      }
    }
  }
}

// ---------------- banded attention via residue-class MFMA flash ----------------
// One block = 32 query rows of one (b, h, residue) subsequence; 2 waves x 16 rows.
// Window in subsequence coords: jj in [i+1, i+64] relative to p0 = t0-32.
__global__ __launch_bounds__(128) void banded_attn_mfma(
    const ushort* __restrict__ qp, const ushort* __restrict__ kp,
    const ushort* __restrict__ vp, ushort* __restrict__ ao) {
  __shared__ ushort Qs[32 * 128];    // 8 KB
  __shared__ ushort Ks[96 * 128];    // 24 KB
  __shared__ ushort Vs[112 * 128];   // 28 KB (rows 96..111 clamped; only hit P=0 zone)
  __shared__ ushort Ps[2][16 * 104]; // 6.5 KB, padded stride 104
  __shared__ ushort Os[2][16 * 128]; // 8 KB

  const int tid = threadIdx.x;
  const int wv = tid >> 6;
  const int lane = tid & 63;
  const int lrow = lane & 15, kgrp = lane >> 4;

  const int blk = blockIdx.x;
  const int chunk = blk & 63;
  const int h = (blk >> 6) & 7;
  const int b = blk >> 9;
  const int sh = h >> 1;
  const int dil = 1 << sh;
  const int Ld = LQ >> sh;
  const int rres = chunk >> (6 - sh);
  const int tile = chunk & ((64 >> sh) - 1);
  const int t0 = tile << 5;
  const int p0 = t0 - 32;

  const size_t headoff = (size_t)h * DH;
  const size_t bbase = (size_t)b * LQ * (NH * DH);

  // ---- staging: Q rows 0..31 (8 instrs), K rows 0..95 (24), V rows 0..111 (28) ----
  const int srow = lane >> 4;  // row within 4-row group
  const int sc = lane & 15;    // 16B chunk slot
  for (int it = wv; it < 60; it += 2) {
    int rbase, pstart;
    const ushort* g;
    ushort* ld;
    if (it < 8) {
      rbase = it * 4; pstart = t0; g = qp; ld = Qs;
    } else if (it < 32) {
      rbase = (it - 8) * 4; pstart = p0; g = kp; ld = Ks;
    } else {
      rbase = (it - 32) * 4; pstart = p0; g = vp; ld = Vs;
    }
    int row = rbase + srow;
    int key = (row ^ (row >> 3)) & 7;
    int cs = sc ^ key;  // pre-swizzled global source chunk
    int t = pstart + row;
    t = t < 0 ? 0 : (t >= Ld ? Ld - 1 : t);
    int l = rres + t * dil;
    const ushort* src = g + bbase + (size_t)l * (NH * DH) + headoff + cs * 8;
    __builtin_amdgcn_global_load_lds(
        (const __attribute__((address_space(1))) void*)src,
        (__attribute__((address_space(3))) void*)(ld + rbase * 128), 16, 0, 0);
  }
  __syncthreads();

  // ---- QK^T: wave wv covers query rows iblk..iblk+15, K tiles (wv+t), t<5 ----
  const int iblk = wv << 4;
  f32x4 accs[5] = {};
#pragma unroll
  for (int ks = 0; ks < 4; ++ks) {
    const int qrow = iblk + lrow;
    const int qslot = (ks * 4 + kgrp) ^ ((qrow ^ (qrow >> 3)) & 7);
    short8 qf = *(const short8*)(Qs + qrow * 128 + qslot * 8);
#pragma unroll
    for (int t = 0; t < 5; ++t) {
      const int krow = (wv + t) * 16 + lrow;
      const int kslot = (ks * 4 + kgrp) ^ ((krow ^ (krow >> 3)) & 7);
      short8 kf = *(const short8*)(Ks + krow * 128 + kslot * 8);
      accs[t] = __builtin_amdgcn_mfma_f32_16x16x32_bf16(qf, kf, accs[t], 0, 0, 0);
    }
  }

  // ---- mask + wave-parallel softmax (16-lane-group reduce) ----
  float dens[4];
#pragma unroll
  for (int j = 0; j < 4; ++j) {
    const int i_b = iblk + kgrp * 4 + j;
    float mj = -1e30f;
#pragma unroll
    for (int t = 0; t < 5; ++t) {
      const int jj = (wv + t) * 16 + lrow;
      const int p = p0 + jj;
      const bool ok = (jj >= i_b + 1) && (jj <= i_b + 64) && (p >= 0) && (p < Ld);
      float v = ok ? accs[t][j] : -1e30f;
      accs[t][j] = v;
      mj = fmaxf(mj, v);
    }
#pragma unroll
    for (int off = 1; off < 16; off <<= 1) mj = fmaxf(mj, __shfl_xor(mj, off));
    float dj = 0.f;
#pragma unroll
    for (int t = 0; t < 5; ++t) {
      float e = __expf(accs[t][j] - mj);
      accs[t][j] = e;
      dj += e;
    }
#pragma unroll
    for (int off = 1; off < 16; off <<= 1) dj += __shfl_xor(dj, off);
    dens[j] = dj;
  }

  // ---- P -> LDS (bf16), plus zero tile cols 80..95 ----
  ushort* Pw = Ps[wv];
#pragma unroll
  for (int j = 0; j < 4; ++j) {
    const int prow = kgrp * 4 + j;
#pragma unroll
    for (int t = 0; t < 5; ++t) Pw[prow * 104 + t * 16 + lrow] = f2bf(accs[t][j]);
    Pw[prow * 104 + 80 + lrow] = 0;
  }

  // ---- PV: A = P rows (local cols 0..95), B = V rows jj = iblk + k ----
  f32x4 accv[8] = {};
#pragma unroll
  for (int ks = 0; ks < 3; ++ks) {
    short8 pf = *(const short8*)(Pw + lrow * 104 + ks * 32 + kgrp * 8);
#pragma unroll
    for (int dt = 0; dt < 8; ++dt) {
      short8 vf;
#pragma unroll
      for (int rr = 0; rr < 8; ++rr) {
        const int vrow = iblk + ks * 32 + kgrp * 8 + rr;
        const int d = dt * 16 + lrow;
        const int slot = (d >> 3) ^ ((vrow ^ (vrow >> 3)) & 7);
        vf[rr] = (short)Vs[vrow * 128 + slot * 8 + (d & 7)];
      }
      accv[dt] = __builtin_amdgcn_mfma_f32_16x16x32_bf16(pf, vf, accv[dt], 0, 0, 0);
    }
  }

  // ---- epilogue: scale by 1/den, through LDS, coalesced 16B stores ----
  ushort* Ow = Os[wv];
#pragma unroll
  for (int j = 0; j < 4; ++j) {
    const float inv = 1.f / dens[j];
    const int orow = kgrp * 4 + j;
#pragma unroll
    for (int dt = 0; dt < 8; ++dt)
      Ow[orow * 128 + dt * 16 + lrow] = f2bf(accv[dt][j] * inv);
  }
#pragma unroll
  for (int pass = 0; pass < 4; ++pass) {
    const int i_loc = pass * 4 + srow;
    const int tq = t0 + iblk + i_loc;
    const int l = rres + tq * dil;
    short8 vvv = *(const short8*)(Ow + i_loc * 128 + sc * 8);
    *(short8*)(ao + bbase + (size_t)l * (NH * DH) + headoff + sc * 8) = vvv;
  }
}

// ---------------- launch ----------------
extern "C" void kernel_launch(void* const* d_in, const int* in_sizes, int n_in,
                              void* d_out, int out_size, void* d_ws, size_t ws_size,
                              hipStream_t stream) {
  const float* q = (const float*)d_in[0];
  const float* k = (const float*)d_in[1];
  const float* v = (const float*)d_in[2];
  const float* Wq = (const float*)d_in[3];
  const float* bq = (const float*)d_in[4];
  const float* Wk = (const float*)d_in[5];
  const float* bk = (const float*)d_in[6];
  const float* Wv = (const float*)d_in[7];
  const float* bv = (const float*)d_in[8];
  const float* Wc = (const float*)d_in[9];
  const float* bc = (const float*)d_in[10];

  const size_t NIN = (size_t)NB * LQ * DMODEL;
  const size_t NW = (size_t)NH * DH * DMODEL;

  ushort* qin = (ushort*)d_ws;
  ushort* kin = qin + NIN;
  ushort* vin = kin + NIN;
  ushort* wqb = vin + NIN;
  ushort* wkb = wqb + NW;
  ushort* wvb = wkb + NW;
  ushort* wcb = wvb + NW;
  ushort* qp = wcb + NW;
  ushort* kp = qp + NIN;
  ushort* vp = kp + NIN;
  ushort* aob = vp + NIN;

  hipLaunchKernelGGL(cvt_qkv, dim3(2048), dim3(256), 0, stream,
                     (const float4*)q, (const float4*)k, (const float4*)v,
                     qin, kin, vin, (int)(NIN / 4));
  hipLaunchKernelGGL(cvt_w, dim3(1024), dim3(256), 0, stream,
                     (const float4*)Wq, (const float4*)Wk, (const float4*)Wv, (const float4*)Wc,
                     wqb, wkb, wvb, wcb, (int)(NW / 4));

  dim3 g1(DMODEL / 128, (NB * LQ) / 128, 3);
  hipLaunchKernelGGL((gemm_bt<1>), g1, dim3(256), 0, stream,
                     qin, wqb, bq, (void*)qp,
                     kin, wkb, bk, (void*)kp,
                     vin, wvb, bv, (void*)vp,
                     NB * LQ, DMODEL, DMODEL);

  hipLaunchKernelGGL(banded_attn_mfma, dim3(NB * NH * 64), dim3(128), 0, stream,
                     qp, kp, vp, aob);

  dim3 g2(DMODEL / 128, (NB * LQ) / 128, 1);
  hipLaunchKernelGGL((gemm_bt<0>), g2, dim3(256), 0, stream,
                     aob, wcb, bc, d_out,
                     aob, wcb, bc, d_out,
                     aob, wcb, bc, d_out,
                     NB * LQ, DMODEL, DMODEL);
}

// Round 3
// 101.091 us; speedup vs baseline: 2.4560x; 1.0578x over previous
//
#include <hip/hip_runtime.h>
#include <hip/hip_bf16.h>
#include <stdint.h>

#define NB 2
#define LQ 2048
#define DMODEL 1024
#define NH 8
#define DH 128
#define KWIN 64

typedef __attribute__((ext_vector_type(8))) short short8;
typedef __attribute__((ext_vector_type(4))) float f32x4;

__device__ __forceinline__ ushort f2bf(float f) {
  uint u = __float_as_uint(f);
  return (ushort)((u + 0x7fffu + ((u >> 16) & 1u)) >> 16);
}
__device__ __forceinline__ float bflo(uint u) { return __uint_as_float(u << 16); }
__device__ __forceinline__ float bfhi(uint u) { return __uint_as_float(u & 0xffff0000u); }

// ---------------- conversion kernels (f32 -> bf16) ----------------
__global__ void cvt_qkv(const float4* __restrict__ a, const float4* __restrict__ b,
                        const float4* __restrict__ c, ushort* __restrict__ da,
                        ushort* __restrict__ db, ushort* __restrict__ dc, int n4) {
  int stride = gridDim.x * blockDim.x;
  for (int i = blockIdx.x * blockDim.x + threadIdx.x; i < n4; i += stride) {
    float4 x = a[i], y = b[i], z = c[i];
    *(ushort4*)(da + 4 * (size_t)i) = make_ushort4(f2bf(x.x), f2bf(x.y), f2bf(x.z), f2bf(x.w));
    *(ushort4*)(db + 4 * (size_t)i) = make_ushort4(f2bf(y.x), f2bf(y.y), f2bf(y.z), f2bf(y.w));
    *(ushort4*)(dc + 4 * (size_t)i) = make_ushort4(f2bf(z.x), f2bf(z.y), f2bf(z.z), f2bf(z.w));
  }
}

__global__ void cvt_w(const float4* __restrict__ a, const float4* __restrict__ b,
                      const float4* __restrict__ c, const float4* __restrict__ d,
                      ushort* __restrict__ da, ushort* __restrict__ db,
                      ushort* __restrict__ dc, ushort* __restrict__ dd, int n4) {
  int stride = gridDim.x * blockDim.x;
  for (int i = blockIdx.x * blockDim.x + threadIdx.x; i < n4; i += stride) {
    float4 x = a[i], y = b[i], z = c[i], w = d[i];
    *(ushort4*)(da + 4 * (size_t)i) = make_ushort4(f2bf(x.x), f2bf(x.y), f2bf(x.z), f2bf(x.w));
    *(ushort4*)(db + 4 * (size_t)i) = make_ushort4(f2bf(y.x), f2bf(y.y), f2bf(y.z), f2bf(y.w));
    *(ushort4*)(dc + 4 * (size_t)i) = make_ushort4(f2bf(z.x), f2bf(z.y), f2bf(z.z), f2bf(z.w));
    *(ushort4*)(dd + 4 * (size_t)i) = make_ushort4(f2bf(w.x), f2bf(w.y), f2bf(w.z), f2bf(w.w));
  }
}

// ---------------- bf16 MFMA GEMM: C[M,N] = A[M,K] * Bt[N,K]^T + bias[N] ----------------
// 128x128 tile, BK=32, double-buffered LDS with issue-early prefetch (T3-minimum),
// XCD-chunked bijective block swizzle (T1). blockIdx.z selects pointer set (fused QKV).
template <int OUT_BF16>
__global__ __launch_bounds__(256, 4) void gemm_bt(
    const ushort* __restrict__ A0, const ushort* __restrict__ B0,
    const float* __restrict__ c0, void* __restrict__ D0,
    const ushort* __restrict__ A1, const ushort* __restrict__ B1,
    const float* __restrict__ c1, void* __restrict__ D1,
    const ushort* __restrict__ A2, const ushort* __restrict__ B2,
    const float* __restrict__ c2, void* __restrict__ D2,
    int M, int N, int Kd) {
  // ---- XCD-chunked swizzle over the flat grid (nblk divisible by 8) ----
  const int gx = gridDim.x, gy = gridDim.y;
  const int nblk = gx * gy * gridDim.z;
  const int fid = (blockIdx.z * gy + blockIdx.y) * gx + blockIdx.x;
  const int cpx = nblk >> 3;
  const int nid = (fid & 7) * cpx + (fid >> 3);
  const int z = nid / (gx * gy);
  const int rem = nid % (gx * gy);
  const int m0 = (rem / gx) * 128;
  const int n0 = (rem % gx) * 128;

  const ushort* A = (z == 0) ? A0 : ((z == 1) ? A1 : A2);
  const ushort* Bt = (z == 0) ? B0 : ((z == 1) ? B1 : B2);
  const float* bias = (z == 0) ? c0 : ((z == 1) ? c1 : c2);
  void* Cv = (z == 0) ? D0 : ((z == 1) ? D1 : D2);

  __shared__ ushort As[2][128 * 32];
  __shared__ ushort Bs[2][128 * 32];

  const int tid = threadIdx.x;
  const int wave = tid >> 6, lane = tid & 63;
  const int wm = wave >> 1, wn = wave & 1;
  const int lrow = lane & 15, kgrp = lane >> 4;

  // staging geometry: thread t stages 16B at byte t*16 (+4096 for second half)
  const int b0 = tid * 16;
  const int b1 = b0 + 4096;
  const int r0 = b0 >> 6, cc0 = (b0 & 63) >> 1;
  const int r1 = b1 >> 6, cc1 = (b1 & 63) >> 1;

  const ushort* gA0 = A + (size_t)(m0 + r0) * Kd + cc0;
  const ushort* gA1 = A + (size_t)(m0 + r1) * Kd + cc1;
  const ushort* gB0 = Bt + (size_t)(n0 + r0) * Kd + cc0;
  const ushort* gB1 = Bt + (size_t)(n0 + r1) * Kd + cc1;

  auto stage = [&](int buf, int kt) {
    __builtin_amdgcn_global_load_lds(
        (const __attribute__((address_space(1))) void*)(gA0 + kt),
        (__attribute__((address_space(3))) void*)(As[buf] + (b0 >> 1)), 16, 0, 0);
    __builtin_amdgcn_global_load_lds(
        (const __attribute__((address_space(1))) void*)(gA1 + kt),
        (__attribute__((address_space(3))) void*)(As[buf] + (b1 >> 1)), 16, 0, 0);
    __builtin_amdgcn_global_load_lds(
        (const __attribute__((address_space(1))) void*)(gB0 + kt),
        (__attribute__((address_space(3))) void*)(Bs[buf] + (b0 >> 1)), 16, 0, 0);
    __builtin_amdgcn_global_load_lds(
        (const __attribute__((address_space(1))) void*)(gB1 + kt),
        (__attribute__((address_space(3))) void*)(Bs[buf] + (b1 >> 1)), 16, 0, 0);
  };

  f32x4 acc[4][4] = {};

  auto compute = [&](int buf) {
    short8 af[4], bfr[4];
#pragma unroll
    for (int m = 0; m < 4; ++m)
      af[m] = *(const short8*)(As[buf] + (wm * 64 + m * 16 + lrow) * 32 + kgrp * 8);
#pragma unroll
    for (int n = 0; n < 4; ++n)
      bfr[n] = *(const short8*)(Bs[buf] + (wn * 64 + n * 16 + lrow) * 32 + kgrp * 8);
#pragma unroll
    for (int m = 0; m < 4; ++m)
#pragma unroll
      for (int n = 0; n < 4; ++n)
        acc[m][n] = __builtin_amdgcn_mfma_f32_16x16x32_bf16(af[m], bfr[n], acc[m][n], 0, 0, 0);
  };

  const int nt = Kd >> 5;  // K tiles of 32
  stage(0, 0);
  __syncthreads();  // drain prologue loads
  int cur = 0;
  for (int it = 0; it < nt - 1; ++it) {
    stage(cur ^ 1, (it + 1) << 5);  // issue next-tile loads EARLY (hide under MFMA)
    compute(cur);
    __syncthreads();  // drains vmcnt (next buf ready) + lgkm (this buf free)
    cur ^= 1;
  }
  compute(cur);  // last tile, no prefetch

  // epilogue: C/D layout col=lane&15, row=(lane>>4)*4+j
  const int cbase = n0 + wn * 64;
  const int rbase = m0 + wm * 64;
  float bv[4];
#pragma unroll
  for (int n = 0; n < 4; ++n) bv[n] = bias[cbase + n * 16 + lrow];

#pragma unroll
  for (int m = 0; m < 4; ++m) {
#pragma unroll
    for (int n = 0; n < 4; ++n) {
      const int col = cbase + n * 16 + lrow;
#pragma unroll
      for (int j = 0; j < 4; ++j) {
        const int row = rbase + m * 16 + kgrp * 4 + j;
        float val = acc[m][n][j] + bv[n];
        if (OUT_BF16) {
          ((ushort*)Cv)[(size_t)row * N + col] = f2bf(val);
        } else {
          ((float*)Cv)[(size_t)row * N + col] = val;
        }
      }
    }
  }
}

// ---------------- banded attention via residue-class MFMA flash ----------------
__global__ __launch_bounds__(128) void banded_attn_mfma(
    const ushort* __restrict__ qp, const ushort* __restrict__ kp,
    const ushort* __restrict__ vp, ushort* __restrict__ ao) {
  __shared__ ushort Qs[32 * 128];
  __shared__ ushort Ks[96 * 128];
  __shared__ ushort Vs[112 * 128];
  __shared__ ushort Ps[2][16 * 104];
  __shared__ ushort Os[2][16 * 128];

  const int tid = threadIdx.x;
  const int wv = tid >> 6;
  const int lane = tid & 63;
  const int lrow = lane & 15, kgrp = lane >> 4;

  const int blk = blockIdx.x;
  const int chunk = blk & 63;
  const int h = (blk >> 6) & 7;
  const int b = blk >> 9;
  const int sh = h >> 1;
  const int dil = 1 << sh;
  const int Ld = LQ >> sh;
  const int rres = chunk >> (6 - sh);
  const int tile = chunk & ((64 >> sh) - 1);
  const int t0 = tile << 5;
  const int p0 = t0 - 32;

  const size_t headoff = (size_t)h * DH;
  const size_t bbase = (size_t)b * LQ * (NH * DH);

  const int srow = lane >> 4;
  const int sc = lane & 15;
  for (int it = wv; it < 60; it += 2) {
    int rbase, pstart;
    const ushort* g;
    ushort* ld;
    if (it < 8) {
      rbase = it * 4; pstart = t0; g = qp; ld = Qs;
    } else if (it < 32) {
      rbase = (it - 8) * 4; pstart = p0; g = kp; ld = Ks;
    } else {
      rbase = (it - 32) * 4; pstart = p0; g = vp; ld = Vs;
    }
    int row = rbase + srow;
    int key = (row ^ (row >> 3)) & 7;
    int cs = sc ^ key;
    int t = pstart + row;
    t = t < 0 ? 0 : (t >= Ld ? Ld - 1 : t);
    int l = rres + t * dil;
    const ushort* src = g + bbase + (size_t)l * (NH * DH) + headoff + cs * 8;
    __builtin_amdgcn_global_load_lds(
        (const __attribute__((address_space(1))) void*)src,
        (__attribute__((address_space(3))) void*)(ld + rbase * 128), 16, 0, 0);
  }
  __syncthreads();

  const int iblk = wv << 4;
  f32x4 accs[5] = {};
#pragma unroll
  for (int ks = 0; ks < 4; ++ks) {
    const int qrow = iblk + lrow;
    const int qslot = (ks * 4 + kgrp) ^ ((qrow ^ (qrow >> 3)) & 7);
    short8 qf = *(const short8*)(Qs + qrow * 128 + qslot * 8);
#pragma unroll
    for (int t = 0; t < 5; ++t) {
      const int krow = (wv + t) * 16 + lrow;
      const int kslot = (ks * 4 + kgrp) ^ ((krow ^ (krow >> 3)) & 7);
      short8 kf = *(const short8*)(Ks + krow * 128 + kslot * 8);
      accs[t] = __builtin_amdgcn_mfma_f32_16x16x32_bf16(qf, kf, accs[t], 0, 0, 0);
    }
  }

  float dens[4];
#pragma unroll
  for (int j = 0; j < 4; ++j) {
    const int i_b = iblk + kgrp * 4 + j;
    float mj = -1e30f;
#pragma unroll
    for (int t = 0; t < 5; ++t) {
      const int jj = (wv + t) * 16 + lrow;
      const int p = p0 + jj;
      const bool ok = (jj >= i_b + 1) && (jj <= i_b + 64) && (p >= 0) && (p < Ld);
      float v = ok ? accs[t][j] : -1e30f;
      accs[t][j] = v;
      mj = fmaxf(mj, v);
    }
#pragma unroll
    for (int off = 1; off < 16; off <<= 1) mj = fmaxf(mj, __shfl_xor(mj, off));
    float dj = 0.f;
#pragma unroll
    for (int t = 0; t < 5; ++t) {
      float e = __expf(accs[t][j] - mj);
      accs[t][j] = e;
      dj += e;
    }
#pragma unroll
    for (int off = 1; off < 16; off <<= 1) dj += __shfl_xor(dj, off);
    dens[j] = dj;
  }

  ushort* Pw = Ps[wv];
#pragma unroll
  for (int j = 0; j < 4; ++j) {
    const int prow = kgrp * 4 + j;
#pragma unroll
    for (int t = 0; t < 5; ++t) Pw[prow * 104 + t * 16 + lrow] = f2bf(accs[t][j]);
    Pw[prow * 104 + 80 + lrow] = 0;
  }

  f32x4 accv[8] = {};
#pragma unroll
  for (int ks = 0; ks < 3; ++ks) {
    short8 pf = *(const short8*)(Pw + lrow * 104 + ks * 32 + kgrp * 8);
#pragma unroll
    for (int dt = 0; dt < 8; ++dt) {
      short8 vf;
#pragma unroll
      for (int rr = 0; rr < 8; ++rr) {
        const int vrow = iblk + ks * 32 + kgrp * 8 + rr;
        const int d = dt * 16 + lrow;
        const int slot = (d >> 3) ^ ((vrow ^ (vrow >> 3)) & 7);
        vf[rr] = (short)Vs[vrow * 128 + slot * 8 + (d & 7)];
      }
      accv[dt] = __builtin_amdgcn_mfma_f32_16x16x32_bf16(pf, vf, accv[dt], 0, 0, 0);
    }
  }

  ushort* Ow = Os[wv];
#pragma unroll
  for (int j = 0; j < 4; ++j) {
    const float inv = 1.f / dens[j];
    const int orow = kgrp * 4 + j;
#pragma unroll
    for (int dt = 0; dt < 8; ++dt)
      Ow[orow * 128 + dt * 16 + lrow] = f2bf(accv[dt][j] * inv);
  }
#pragma unroll
  for (int pass = 0; pass < 4; ++pass) {
    const int i_loc = pass * 4 + srow;
    const int tq = t0 + iblk + i_loc;
    const int l = rres + tq * dil;
    short8 vvv = *(const short8*)(Ow + i_loc * 128 + sc * 8);
    *(short8*)(ao + bbase + (size_t)l * (NH * DH) + headoff + sc * 8) = vvv;
  }
}

// ---------------- launch ----------------
extern "C" void kernel_launch(void* const* d_in, const int* in_sizes, int n_in,
                              void* d_out, int out_size, void* d_ws, size_t ws_size,
                              hipStream_t stream) {
  const float* q = (const float*)d_in[0];
  const float* k = (const float*)d_in[1];
  const float* v = (const float*)d_in[2];
  const float* Wq = (const float*)d_in[3];
  const float* bq = (const float*)d_in[4];
  const float* Wk = (const float*)d_in[5];
  const float* bk = (const float*)d_in[6];
  const float* Wv = (const float*)d_in[7];
  const float* bv = (const float*)d_in[8];
  const float* Wc = (const float*)d_in[9];
  const float* bc = (const float*)d_in[10];

  const size_t NIN = (size_t)NB * LQ * DMODEL;
  const size_t NW = (size_t)NH * DH * DMODEL;

  ushort* qin = (ushort*)d_ws;
  ushort* kin = qin + NIN;
  ushort* vin = kin + NIN;
  ushort* wqb = vin + NIN;
  ushort* wkb = wqb + NW;
  ushort* wvb = wkb + NW;
  ushort* wcb = wvb + NW;
  ushort* qp = wcb + NW;
  ushort* kp = qp + NIN;
  ushort* vp = kp + NIN;
  ushort* aob = vp + NIN;

  hipLaunchKernelGGL(cvt_qkv, dim3(2048), dim3(256), 0, stream,
                     (const float4*)q, (const float4*)k, (const float4*)v,
                     qin, kin, vin, (int)(NIN / 4));
  hipLaunchKernelGGL(cvt_w, dim3(1024), dim3(256), 0, stream,
                     (const float4*)Wq, (const float4*)Wk, (const float4*)Wv, (const float4*)Wc,
                     wqb, wkb, wvb, wcb, (int)(NW / 4));

  dim3 g1(DMODEL / 128, (NB * LQ) / 128, 3);
  hipLaunchKernelGGL((gemm_bt<1>), g1, dim3(256), 0, stream,
                     qin, wqb, bq, (void*)qp,
                     kin, wkb, bk, (void*)kp,
                     vin, wvb, bv, (void*)vp,
                     NB * LQ, DMODEL, DMODEL);

  hipLaunchKernelGGL(banded_attn_mfma, dim3(NB * NH * 64), dim3(128), 0, stream,
                     qp, kp, vp, aob);

  dim3 g2(DMODEL / 128, (NB * LQ) / 128, 1);
  hipLaunchKernelGGL((gemm_bt<0>), g2, dim3(256), 0, stream,
                     aob, wcb, bc, d_out,
                     aob, wcb, bc, d_out,
                     aob, wcb, bc, d_out,
                     NB * LQ, DMODEL, DMODEL);
}